// Round 2
// baseline (132.845 us; speedup 1.0000x reference)
//
#include <hip/hip_runtime.h>
#include <hip/hip_cooperative_groups.h>
#include <math.h>

namespace cg = cooperative_groups;

constexpr int Lc = 8192;   // sequence length
constexpr int Kc = 32;     // eigenvectors
constexpr int Bc = 64;     // batch
constexpr int NSLICE = 32; // conv tap-slices (128 odd taps each)
constexpr int NCHUNK = 8;  // conv n-chunks (1024 outputs each)

// cot(pi*d/L) in fp32, reflected for d > L/2 to avoid cancellation near pi.
__device__ inline float cot_pi_frac_f(int d) {
    int dd = d; float s = 1.0f;
    if (dd > Lc / 2) { dd = Lc - dd; s = -1.0f; }
    float ang = (float)(M_PI * (double)dd / (double)Lc);
    return s * __fdividef(__cosf(ang), __sinf(ang));
}

// Math (validated R1-R3 of previous session):
//   out[b][n] = sr[b]*w[n] + si2[b]*Bsum[n]
//   w[n]   = sum_k lam[k] ev[k][n]
//   sr[b]  = sum_{even n} u[b][n] + 4096*u[b][0]      (DC weight 4097)
//   si2[b] = (2/L) * sum_m u[b][2m+1] * c[m],  c[m] = cot(pi(2m+1)/L)
//   Bsum[n]= sum_m c[m] * w[(n-2m-1) mod L]           (signs absorbed)
//
// Fused single cooperative kernel, 256 blocks x 256 threads (1 block/CU):
//   phase 1: blocks 0..63 sigma(b), blocks 64..95 w-chunk  -> sr,si2,wbuf
//   grid.sync()
//   phase 2: all blocks conv slice (cn=blk&7, sl=blk>>3)   -> Bp partials
//   grid.sync()
//   phase 3: all blocks reduce 32 partials + rank-2 epilogue -> out
// Bodies are identical to the previously-verified 3-kernel version.

__global__ __launch_bounds__(256) void k_fused(
    const float* __restrict__ u, const float* __restrict__ ev,
    const float* __restrict__ lam, float* __restrict__ out,
    float* __restrict__ sr, float* __restrict__ si2,
    float* __restrict__ wbuf, float* __restrict__ Bp)
{
    cg::grid_group grid = cg::this_grid();
    const int t = threadIdx.x;
    const int blk = blockIdx.x;

    __shared__ float s_we[643];               // s_we[j] = w[A + 2j]
    __shared__ float s_wo[643];               // s_wo[j] = w[A + 2j + 1]
    __shared__ __align__(16) float s_c[128];  // reversed tap slice
    __shared__ float red[8];                  // sigma reduction
    __shared__ float s_sv[128];               // sr|si2 stage (phase 3)

    // ---------------- phase 1: sigma + w precompute ----------------
    if (blk < 64) {
        const int b = blk;
        const float4* u4 = (const float4*)(u + (size_t)b * Lc);
        float ar0 = 0.f, ar1 = 0.f, ai0 = 0.f, ai1 = 0.f;
#pragma unroll
        for (int i = 0; i < 8; ++i) {
            int j = t + 256 * i;
            float4 v = u4[j];
            ar0 += v.x; ar1 += v.z;
            ai0 = fmaf(v.y, cot_pi_frac_f(4 * j + 1), ai0);
            ai1 = fmaf(v.w, cot_pi_frac_f(4 * j + 3), ai1);
        }
        if (t == 0) ar0 += 4096.0f * u[(size_t)b * Lc];
        float ar = ar0 + ar1, ai = ai0 + ai1;
        for (int off = 32; off > 0; off >>= 1) {
            ar += __shfl_down(ar, off);
            ai += __shfl_down(ai, off);
        }
        int wave = t >> 6, lane = t & 63;
        if (lane == 0) { red[wave] = ar; red[4 + wave] = ai; }
        __syncthreads();
        if (t == 0) {
            sr[b]  = red[0] + red[1] + red[2] + red[3];
            si2[b] = (2.0f / (float)Lc) * (red[4] + red[5] + red[6] + red[7]);
        }
    } else if (blk < 96) {
        const int n = (blk - 64) * 256 + t;
        float wv = 0.f;
#pragma unroll
        for (int k = 0; k < Kc; ++k)
            wv = fmaf(lam[k], ev[(size_t)k * Lc + n], wv);
        wbuf[n] = wv;
    }

    grid.sync();

    // ---------------- phase 2: conv (register-tiled circular FIR) ----------
    {
        const int cn = blk & (NCHUNK - 1);
        const int sl = blk >> 3;
        const int n0 = cn * 1024;
        const int dbase = sl * 256;
        const int A = n0 - dbase - 256;           // 4-aligned window base

        // w-window: w[A .. A+1279] via float4 loads from precomputed wbuf.
#pragma unroll
        for (int it = 0; it < 2; ++it) {
            int gq = t + 256 * it;
            if (gq < 320) {
                int pos = (A + 4 * gq + 2 * Lc) & (Lc - 1);  // no wrap inside quad
                float4 v = *(const float4*)(wbuf + pos);
                s_we[2 * gq]     = v.x; s_wo[2 * gq]     = v.y;
                s_we[2 * gq + 1] = v.z; s_wo[2 * gq + 1] = v.w;
            }
        }
        // Reversed tap slice: s_c[mm] = cot(pi*(dbase + 255 - 2mm)/L)
        if (t < 128) s_c[t] = cot_pi_frac_f(dbase + 255 - 2 * t);
        __syncthreads();

        // Thread t: g=t>>1, p=t&1; outputs n0+8g+p+2r, r=0..3, 7-reg window.
        const int g = t >> 1, p = t & 1;
        const float* s_wp = p ? (s_we + 1) : s_wo;   // parity remap (A=wbase-1)
        const int jb = 4 * g;

        float W0 = s_wp[jb],     W1 = s_wp[jb + 1], W2 = s_wp[jb + 2], W3 = s_wp[jb + 3];
        float W4 = s_wp[jb + 4], W5 = s_wp[jb + 5], W6 = s_wp[jb + 6];
        float a0 = 0.f, a1 = 0.f, a2 = 0.f, a3 = 0.f;

        const float4* s_c4 = (const float4*)s_c;
#pragma unroll
        for (int G = 0; G < 32; ++G) {
            const int mm0 = 4 * G;
            float4 cv = s_c4[G];                     // one ds_read_b128
            a0 = fmaf(cv.x, W0, a0); a1 = fmaf(cv.x, W1, a1); a2 = fmaf(cv.x, W2, a2); a3 = fmaf(cv.x, W3, a3);
            a0 = fmaf(cv.y, W1, a0); a1 = fmaf(cv.y, W2, a1); a2 = fmaf(cv.y, W3, a2); a3 = fmaf(cv.y, W4, a3);
            a0 = fmaf(cv.z, W2, a0); a1 = fmaf(cv.z, W3, a1); a2 = fmaf(cv.z, W4, a2); a3 = fmaf(cv.z, W5, a3);
            a0 = fmaf(cv.w, W3, a0); a1 = fmaf(cv.w, W4, a1); a2 = fmaf(cv.w, W5, a2); a3 = fmaf(cv.w, W6, a3);
            if (G < 31) {
                W0 = W4; W1 = W5; W2 = W6;
                W3 = s_wp[jb + mm0 + 7];  W4 = s_wp[jb + mm0 + 8];
                W5 = s_wp[jb + mm0 + 9];  W6 = s_wp[jb + mm0 + 10];
            }
        }
        float* dst = Bp + (size_t)sl * Lc + n0 + 8 * g + p;
        dst[0] = a0; dst[2] = a1; dst[4] = a2; dst[6] = a3;
    }

    grid.sync();

    // ---------------- phase 3: reduce 32 partials + rank-2 epilogue --------
    {
        if (t < 128) s_sv[t] = (t < 64) ? sr[t] : si2[t - 64];
        const int cn = blk & 31, bg = blk >> 5;
        const int n = cn * 256 + t;
        float wv = wbuf[n];
        float bsum = 0.f;
#pragma unroll
        for (int s = 0; s < NSLICE; ++s) bsum += Bp[(size_t)s * Lc + n];
        __syncthreads();
#pragma unroll
        for (int j = 0; j < 8; ++j) {
            int b = bg * 8 + j;
            out[(size_t)b * Lc + n] = fmaf(s_sv[b], wv, s_sv[64 + b] * bsum);
        }
    }
}

extern "C" void kernel_launch(void* const* d_in, const int* in_sizes, int n_in,
                              void* d_out, int out_size, void* d_ws, size_t ws_size,
                              hipStream_t stream) {
    const float* u   = (const float*)d_in[0];  // (64, 8192)
    const float* ev  = (const float*)d_in[1];  // (32, 8192)
    const float* lam = (const float*)d_in[2];  // (32,)
    float* out = (float*)d_out;                // (64, 8192)

    float* ws   = (float*)d_ws;
    float* sr   = ws;                   // 64
    float* si2  = ws + 64;              // 64
    float* wbuf = ws + 128;             // 8192 (byte offset 512 -> 16B aligned)
    float* Bp   = ws + 128 + Lc;        // 32 * 8192

    void* args[] = { (void*)&u, (void*)&ev, (void*)&lam, (void*)&out,
                     (void*)&sr, (void*)&si2, (void*)&wbuf, (void*)&Bp };
    hipLaunchCooperativeKernel((void*)k_fused, dim3(256), dim3(256),
                               args, 0, stream);
}

// Round 4
// 66.177 us; speedup vs baseline: 2.0074x; 2.0074x over previous
//
#include <hip/hip_runtime.h>
#include <math.h>

constexpr int Lc = 8192;   // sequence length
constexpr int Kc = 32;     // eigenvectors
constexpr int Bc = 64;     // batch
constexpr int NSLICE = 16; // conv tap-slices (256 odd taps each, FULL 4096 coverage)
constexpr int NCHUNK = 8;  // conv n-chunks (1024 outputs each)

// cot(pi*d/L) in fp32, reflected for d > L/2 to avoid cancellation near pi.
__device__ inline float cot_pi_frac_f(int d) {
    int dd = d; float s = 1.0f;
    if (dd > Lc / 2) { dd = Lc - dd; s = -1.0f; }
    float ang = (float)(M_PI * (double)dd / (double)Lc);
    return s * __fdividef(__cosf(ang), __sinf(ang));
}

// Math (validated R1-R3 of previous session):
//   out[b][n] = sr[b]*w[n] + si2[b]*Bsum[n]
//   w[n]   = sum_k lam[k] ev[k][n]
//   sr[b]  = sum_{even n} u[b][n] + 4096*u[b][0]      (DC weight 4097)
//   si2[b] = (2/L) * sum_m u[b][2m+1] * c[m],  c[m] = cot(pi(2m+1)/L)
//   Bsum[n]= sum_m c[m] * w[(n-2m-1) mod L]           (signs absorbed)
//
// R4 geometry: 16 tap-slices x 8 n-chunks = 128 conv blocks + 64 sigma
// = 192 blocks -> SINGLE round over 256 CUs. Slice sl covers odd taps
// d in [512sl+1, 512sl+511] (256 taps); union over sl=0..15 = all 4096
// odd taps (R3's bug: 8 slices covered only half). Per thread: 4 outputs
// x 256 taps. Index algebra identical in form to validated R1 loop.

// K0: precompute w once.
__global__ __launch_bounds__(256) void k_w(
    const float* __restrict__ ev, const float* __restrict__ lam,
    float* __restrict__ wbuf)
{
    const int n = blockIdx.x * 256 + threadIdx.x;
    float wv = 0.f;
#pragma unroll
    for (int k = 0; k < Kc; ++k)
        wv = fmaf(lam[k], ev[(size_t)k * Lc + n], wv);
    wbuf[n] = wv;
}

// K1: blocks 0..63 = sigma, 64..191 = conv slices (single round).
__global__ __launch_bounds__(256) void k_main(
    const float* __restrict__ u, const float* __restrict__ wbuf,
    float* __restrict__ sr, float* __restrict__ si2, float* __restrict__ Bp)
{
    const int t = threadIdx.x;

    if (blockIdx.x < 64) {
        // ---------------- sigma: per-batch scalar reduction -----------------
        int b = blockIdx.x;
        const float4* u4 = (const float4*)(u + (size_t)b * Lc);
        float ar0 = 0.f, ar1 = 0.f, ai0 = 0.f, ai1 = 0.f;
#pragma unroll
        for (int i = 0; i < 8; ++i) {
            int j = t + 256 * i;
            float4 v = u4[j];
            ar0 += v.x; ar1 += v.z;
            ai0 = fmaf(v.y, cot_pi_frac_f(4 * j + 1), ai0);
            ai1 = fmaf(v.w, cot_pi_frac_f(4 * j + 3), ai1);
        }
        if (t == 0) ar0 += 4096.0f * u[(size_t)b * Lc];
        float ar = ar0 + ar1, ai = ai0 + ai1;
        for (int off = 32; off > 0; off >>= 1) {
            ar += __shfl_down(ar, off);
            ai += __shfl_down(ai, off);
        }
        __shared__ float red[8];
        int wave = t >> 6, lane = t & 63;
        if (lane == 0) { red[wave] = ar; red[4 + wave] = ai; }
        __syncthreads();
        if (t == 0) {
            sr[b]  = red[0] + red[1] + red[2] + red[3];
            si2[b] = (2.0f / (float)Lc) * (red[4] + red[5] + red[6] + red[7]);
        }
        return;
    }

    // ---------------- conv: register-tiled circular FIR ---------------------
    // Window w[A .. A+1535]: s_we[j] = w[A+2j], s_wo[j] = w[A+2j+1], j=0..767.
    __shared__ float s_we[772];
    __shared__ float s_wo[772];
    __shared__ __align__(16) float s_c[256];  // reversed tap slice (256 odd taps)

    const int blk = blockIdx.x - 64;
    const int cn = blk & (NCHUNK - 1);
    const int sl = blk >> 3;                  // 0..15
    const int n0 = cn * 1024;
    const int dbase = sl * 512;
    const int A = n0 - dbase - 512;           // 4-aligned window base

    // Stage 384 float4 = w[A .. A+1535] from precomputed wbuf.
#pragma unroll
    for (int it = 0; it < 2; ++it) {
        int gq = t + 256 * it;
        if (gq < 384) {
            int pos = (A + 4 * gq + 2 * Lc) & (Lc - 1);   // 4-aligned, no wrap inside quad
            float4 v = *(const float4*)(wbuf + pos);
            s_we[2 * gq]     = v.x; s_wo[2 * gq]     = v.y;
            s_we[2 * gq + 1] = v.z; s_wo[2 * gq + 1] = v.w;
        }
    }
    // Reversed tap slice: s_c[mm] = cot(pi*(dbase + 511 - 2mm)/L), mm=0..255
    s_c[t] = cot_pi_frac_f(dbase + 511 - 2 * t);
    __syncthreads();

    // Thread t: g=t>>1, p=t&1; outputs n0+8g+p+2r, r=0..3.
    // Bpartial[n] = sum_mm s_c[mm] * w[A + 1 + p + 2*(4g + r + mm)]
    //   p=0 -> s_wo[4g+r+mm], p=1 -> s_we[4g+r+mm+1].
    const int g = t >> 1, p = t & 1;
    const float* s_wp = p ? (s_we + 1) : s_wo;
    const int jb = 4 * g;

    float W0 = s_wp[jb],     W1 = s_wp[jb + 1], W2 = s_wp[jb + 2], W3 = s_wp[jb + 3];
    float W4 = s_wp[jb + 4], W5 = s_wp[jb + 5], W6 = s_wp[jb + 6];
    float a0 = 0.f, a1 = 0.f, a2 = 0.f, a3 = 0.f;

    const float4* s_c4 = (const float4*)s_c;
#pragma unroll
    for (int G = 0; G < 64; ++G) {
        const int mm0 = 4 * G;
        float4 cv = s_c4[G];                     // one ds_read_b128 (broadcast)
        a0 = fmaf(cv.x, W0, a0); a1 = fmaf(cv.x, W1, a1); a2 = fmaf(cv.x, W2, a2); a3 = fmaf(cv.x, W3, a3);
        a0 = fmaf(cv.y, W1, a0); a1 = fmaf(cv.y, W2, a1); a2 = fmaf(cv.y, W3, a2); a3 = fmaf(cv.y, W4, a3);
        a0 = fmaf(cv.z, W2, a0); a1 = fmaf(cv.z, W3, a1); a2 = fmaf(cv.z, W4, a2); a3 = fmaf(cv.z, W5, a3);
        a0 = fmaf(cv.w, W3, a0); a1 = fmaf(cv.w, W4, a1); a2 = fmaf(cv.w, W5, a2); a3 = fmaf(cv.w, W6, a3);
        if (G < 63) {
            W0 = W4; W1 = W5; W2 = W6;
            W3 = s_wp[jb + mm0 + 7];  W4 = s_wp[jb + mm0 + 8];
            W5 = s_wp[jb + mm0 + 9];  W6 = s_wp[jb + mm0 + 10];
        }
    }
    float* dst = Bp + (size_t)sl * Lc + n0 + 8 * g + p;
    dst[0] = a0; dst[2] = a1; dst[4] = a2; dst[6] = a3;
}

// K2: reduce 16 partials + rank-2 epilogue; w loaded from wbuf.
__global__ __launch_bounds__(256) void k_out(
    const float* __restrict__ wbuf,
    const float* __restrict__ sr, const float* __restrict__ si2,
    const float* __restrict__ Bp, float* __restrict__ out)
{
    __shared__ float s_sv[128];
    const int t = threadIdx.x;
    if (t < 128) s_sv[t] = (t < 64) ? sr[t] : si2[t - 64];
    const int cn = blockIdx.x & 31, bg = blockIdx.x >> 5;
    const int n = cn * 256 + t;
    float wv = wbuf[n];
    float bsum = 0.f;
#pragma unroll
    for (int s = 0; s < NSLICE; ++s) bsum += Bp[(size_t)s * Lc + n];
    __syncthreads();
#pragma unroll
    for (int j = 0; j < 8; ++j) {
        int b = bg * 8 + j;
        out[(size_t)b * Lc + n] = fmaf(s_sv[b], wv, s_sv[64 + b] * bsum);
    }
}

extern "C" void kernel_launch(void* const* d_in, const int* in_sizes, int n_in,
                              void* d_out, int out_size, void* d_ws, size_t ws_size,
                              hipStream_t stream) {
    const float* u   = (const float*)d_in[0];  // (64, 8192)
    const float* ev  = (const float*)d_in[1];  // (32, 8192)
    const float* lam = (const float*)d_in[2];  // (32,)
    float* out = (float*)d_out;                // (64, 8192)

    float* ws   = (float*)d_ws;
    float* sr   = ws;                   // 64
    float* si2  = ws + 64;              // 64
    float* wbuf = ws + 128;             // 8192 (byte offset 512 -> 16B aligned)
    float* Bp   = ws + 128 + Lc;        // 16 * 8192

    hipLaunchKernelGGL(k_w,    dim3(Lc / 256), dim3(256), 0, stream, ev, lam, wbuf);
    hipLaunchKernelGGL(k_main, dim3(64 + NCHUNK * NSLICE), dim3(256), 0, stream,
                       u, wbuf, sr, si2, Bp);
    hipLaunchKernelGGL(k_out,  dim3(256), dim3(256), 0, stream,
                       wbuf, sr, si2, Bp, out);
}

// Round 5
// 65.332 us; speedup vs baseline: 2.0334x; 1.0129x over previous
//
#include <hip/hip_runtime.h>
#include <math.h>

constexpr int Lc = 8192;   // sequence length
constexpr int Kc = 32;     // eigenvectors
constexpr int Bc = 64;     // batch
constexpr int NSLICE = 32; // conv tap-slices (128 odd taps each)
constexpr int NCHUNK = 8;  // conv n-chunks (1024 outputs each)

// cot(pi*d/L) in fp32, reflected for d > L/2 to avoid cancellation near pi.
__device__ inline float cot_pi_frac_f(int d) {
    int dd = d; float s = 1.0f;
    if (dd > Lc / 2) { dd = Lc - dd; s = -1.0f; }
    float ang = (float)(M_PI * (double)dd / (double)Lc);
    return s * __fdividef(__cosf(ang), __sinf(ang));
}

// Math (validated):
//   out[b][n] = sr[b]*w[n] + si2[b]*Bsum[n]
//   w[n]   = sum_k lam[k] ev[k][n]
//   sr[b]  = sum_{even n} u[b][n] + 4096*u[b][0]
//   si2[b] = (2/L) * sum_m u[b][2m+1] * c[m],  c[m] = cot(pi(2m+1)/L)
//   Bsum[n]= sum_m c[m] * w[(n-2m-1) mod L]
//
// R5: conv inner loop re-indexed so the w-refill is ONE aligned ds_read_b128
// per 4 taps (was 4 bank-conflicted ds_read_b32). Parity arrays share index:
//   s_w0[j] = w[A+1+2j]  (p=0),  s_w1[j] = w[A+2+2j]  (p=1), j = 4g+r+mm.
// Sigma moved into K1 alongside w-precompute (independent, latency-bound,
// overlap); k_conv gets a clean 256-block single round on 256 CUs.

// K1: blocks 0..63 = sigma(b), 64..95 = w chunks.
__global__ __launch_bounds__(256) void k_pre(
    const float* __restrict__ u, const float* __restrict__ ev,
    const float* __restrict__ lam, float* __restrict__ sr,
    float* __restrict__ si2, float* __restrict__ wbuf)
{
    const int t = threadIdx.x;
    if (blockIdx.x < 64) {
        int b = blockIdx.x;
        const float4* u4 = (const float4*)(u + (size_t)b * Lc);
        float ar0 = 0.f, ar1 = 0.f, ai0 = 0.f, ai1 = 0.f;
#pragma unroll
        for (int i = 0; i < 8; ++i) {
            int j = t + 256 * i;
            float4 v = u4[j];
            ar0 += v.x; ar1 += v.z;
            ai0 = fmaf(v.y, cot_pi_frac_f(4 * j + 1), ai0);
            ai1 = fmaf(v.w, cot_pi_frac_f(4 * j + 3), ai1);
        }
        if (t == 0) ar0 += 4096.0f * u[(size_t)b * Lc];
        float ar = ar0 + ar1, ai = ai0 + ai1;
        for (int off = 32; off > 0; off >>= 1) {
            ar += __shfl_down(ar, off);
            ai += __shfl_down(ai, off);
        }
        __shared__ float red[8];
        int wave = t >> 6, lane = t & 63;
        if (lane == 0) { red[wave] = ar; red[4 + wave] = ai; }
        __syncthreads();
        if (t == 0) {
            sr[b]  = red[0] + red[1] + red[2] + red[3];
            si2[b] = (2.0f / (float)Lc) * (red[4] + red[5] + red[6] + red[7]);
        }
    } else {
        const int n = (blockIdx.x - 64) * 256 + t;
        float wv = 0.f;
#pragma unroll
        for (int k = 0; k < Kc; ++k)
            wv = fmaf(lam[k], ev[(size_t)k * Lc + n], wv);
        wbuf[n] = wv;
    }
}

// K2: 256 conv blocks (32 slices x 8 chunks), quad-refill inner loop.
__global__ __launch_bounds__(256) void k_conv(
    const float* __restrict__ wbuf, float* __restrict__ Bp)
{
    // s_w0[j] = w[A+1+2j], s_w1[j] = w[A+2+2j], j = 0..639 (quads 0..159).
    __shared__ __align__(16) float s_w0[644];
    __shared__ __align__(16) float s_w1[644];
    __shared__ __align__(16) float s_c[128];  // reversed tap slice

    const int t = threadIdx.x;
    const int cn = blockIdx.x & (NCHUNK - 1);
    const int sl = blockIdx.x >> 3;
    const int n0 = cn * 1024;
    const int dbase = sl * 256;
    const int A = n0 - dbase - 256;           // 4-aligned window base

    // Stage 320 quads = w[A .. A+1279] from wbuf, scattered into parity arrays.
#pragma unroll
    for (int it = 0; it < 2; ++it) {
        int gq = t + 256 * it;
        if (gq < 320) {
            int pos = (A + 4 * gq + 2 * Lc) & (Lc - 1);   // 4-aligned, no wrap inside quad
            float4 v = *(const float4*)(wbuf + pos);
            // v = { w[A+4gq], w[A+4gq+1], w[A+4gq+2], w[A+4gq+3] }
            s_w0[2 * gq]     = v.y;            // w[A+1+2(2gq)]
            s_w0[2 * gq + 1] = v.w;            // w[A+1+2(2gq+1)]
            s_w1[2 * gq]     = v.z;            // w[A+2+2(2gq)]
            if (gq > 0) s_w1[2 * gq - 1] = v.x; // w[A+2+2(2gq-1)]
        }
    }
    // Reversed tap slice: s_c[mm] = cot(pi*(dbase + 255 - 2mm)/L), mm=0..127
    if (t < 128) s_c[t] = cot_pi_frac_f(dbase + 255 - 2 * t);
    __syncthreads();

    // Thread t: g=t>>1, p=t&1; outputs n0+8g+p+2r, r=0..3.
    // Bpartial = sum_mm s_c[mm] * s_wp[4g + r + mm], rolling 2-quad window.
    const int g = t >> 1, p = t & 1;
    const float4* s_w4 = (const float4*)(p ? s_w1 : s_w0);
    const float4* s_c4 = (const float4*)s_c;

    float4 Wa = s_w4[g];        // j = 4g .. 4g+3
    float4 Wb = s_w4[g + 1];    // j = 4g+4 .. 4g+7
    float a0 = 0.f, a1 = 0.f, a2 = 0.f, a3 = 0.f;

#pragma unroll
    for (int G = 0; G < 32; ++G) {
        float4 cv = s_c4[G];                     // broadcast b128
        a0 = fmaf(cv.x, Wa.x, a0); a0 = fmaf(cv.y, Wa.y, a0); a0 = fmaf(cv.z, Wa.z, a0); a0 = fmaf(cv.w, Wa.w, a0);
        a1 = fmaf(cv.x, Wa.y, a1); a1 = fmaf(cv.y, Wa.z, a1); a1 = fmaf(cv.z, Wa.w, a1); a1 = fmaf(cv.w, Wb.x, a1);
        a2 = fmaf(cv.x, Wa.z, a2); a2 = fmaf(cv.y, Wa.w, a2); a2 = fmaf(cv.z, Wb.x, a2); a2 = fmaf(cv.w, Wb.y, a2);
        a3 = fmaf(cv.x, Wa.w, a3); a3 = fmaf(cv.y, Wb.x, a3); a3 = fmaf(cv.z, Wb.y, a3); a3 = fmaf(cv.w, Wb.z, a3);
        if (G < 31) { Wa = Wb; Wb = s_w4[g + G + 2]; }   // one aligned b128 refill
    }
    float* dst = Bp + (size_t)sl * Lc + n0 + 8 * g + p;
    dst[0] = a0; dst[2] = a1; dst[4] = a2; dst[6] = a3;
}

// K3: reduce 32 partials + rank-2 epilogue; w loaded from wbuf.
__global__ __launch_bounds__(256) void k_out(
    const float* __restrict__ wbuf,
    const float* __restrict__ sr, const float* __restrict__ si2,
    const float* __restrict__ Bp, float* __restrict__ out)
{
    __shared__ float s_sv[128];
    const int t = threadIdx.x;
    if (t < 128) s_sv[t] = (t < 64) ? sr[t] : si2[t - 64];
    const int cn = blockIdx.x & 31, bg = blockIdx.x >> 5;
    const int n = cn * 256 + t;
    float wv = wbuf[n];
    float bsum = 0.f;
#pragma unroll
    for (int s = 0; s < NSLICE; ++s) bsum += Bp[(size_t)s * Lc + n];
    __syncthreads();
#pragma unroll
    for (int j = 0; j < 8; ++j) {
        int b = bg * 8 + j;
        out[(size_t)b * Lc + n] = fmaf(s_sv[b], wv, s_sv[64 + b] * bsum);
    }
}

extern "C" void kernel_launch(void* const* d_in, const int* in_sizes, int n_in,
                              void* d_out, int out_size, void* d_ws, size_t ws_size,
                              hipStream_t stream) {
    const float* u   = (const float*)d_in[0];  // (64, 8192)
    const float* ev  = (const float*)d_in[1];  // (32, 8192)
    const float* lam = (const float*)d_in[2];  // (32,)
    float* out = (float*)d_out;                // (64, 8192)

    float* ws   = (float*)d_ws;
    float* sr   = ws;                   // 64
    float* si2  = ws + 64;              // 64
    float* wbuf = ws + 128;             // 8192 (byte offset 512 -> 16B aligned)
    float* Bp   = ws + 128 + Lc;        // 32 * 8192

    hipLaunchKernelGGL(k_pre,  dim3(96),  dim3(256), 0, stream,
                       u, ev, lam, sr, si2, wbuf);
    hipLaunchKernelGGL(k_conv, dim3(NCHUNK * NSLICE), dim3(256), 0, stream,
                       wbuf, Bp);
    hipLaunchKernelGGL(k_out,  dim3(256), dim3(256), 0, stream,
                       wbuf, sr, si2, Bp, out);
}